// Round 16
// baseline (156.764 us; speedup 1.0000x reference)
//
#include <hip/hip_runtime.h>

#define B 64
#define T 256
#define C 384
#define H 6
#define HS 64
#define DFF 1536
#define BT (B*T)

typedef __attribute__((ext_vector_type(8))) short short8;
typedef __attribute__((ext_vector_type(4))) float float4v;
typedef __attribute__((ext_vector_type(4))) unsigned short ushort4v;

static __device__ __forceinline__ unsigned short f2bf(float f) {
  unsigned int u = __float_as_uint(f);
  unsigned int r = (u + 0x7fffu + ((u >> 16) & 1u)) >> 16;
  return (unsigned short)r;
}

typedef __attribute__((address_space(1))) const unsigned int ga_u32;
typedef __attribute__((address_space(3))) unsigned int ls_u32;
static __device__ __forceinline__ void gld16(const void* g, void* l) {
  __builtin_amdgcn_global_load_lds((ga_u32*)g, (ls_u32*)l, 16, 0, 0);
}

// ---------------- weight prep: transpose + f32->bf16 ----------------
__global__ __launch_bounds__(256) void prep_w(
    const float* __restrict__ Wq, const float* __restrict__ Wk, const float* __restrict__ Wv,
    const float* __restrict__ Wo, const float* __restrict__ W1, const float* __restrict__ W2,
    unsigned short* __restrict__ wqkv, unsigned short* __restrict__ wo,
    unsigned short* __restrict__ w1t, unsigned short* __restrict__ w2t) {
  __shared__ float tile[32][33];
  int bx = blockIdx.x;
  int x = threadIdx.x & 31, y = threadIdx.x >> 5;
  if (bx < 432) {  // QKV -> wqkv[1152][384]
    int tn = bx % 36, tc = bx / 36;
    int n0 = tn * 32, c0 = tc * 32;
    int mat = n0 / 384, rem = n0 % 384, head = rem / 64, hs0 = rem % 64;
    const float* W = (mat == 0) ? Wq : ((mat == 1) ? Wk : Wv);
    const float* src = W + (size_t)head * C * HS + hs0;
    #pragma unroll
    for (int i = 0; i < 4; ++i) tile[y + 8 * i][x] = src[(size_t)(c0 + y + 8 * i) * 64 + x];
    __syncthreads();
    #pragma unroll
    for (int i = 0; i < 4; ++i)
      wqkv[(size_t)(n0 + y + 8 * i) * 384 + c0 + x] = f2bf(tile[x][y + 8 * i]);
    return;
  }
  const float* src; unsigned short* dst; int CN, R, n0, c0;
  if (bx < 576) {         // Wo [384][384]
    int t = bx - 432; n0 = (t % 12) * 32; c0 = (t / 12) * 32;
    src = Wo; dst = wo; CN = 384; R = 384;
  } else if (bx < 1152) { // W1 [384][1536]
    int t = bx - 576; n0 = (t % 48) * 32; c0 = (t / 48) * 32;
    src = W1; dst = w1t; CN = 1536; R = 384;
  } else {                // W2 [1536][384]
    int t = bx - 1152; n0 = (t % 12) * 32; c0 = (t / 12) * 32;
    src = W2; dst = w2t; CN = 384; R = 1536;
  }
  #pragma unroll
  for (int i = 0; i < 4; ++i) tile[y + 8 * i][x] = src[(size_t)(c0 + y + 8 * i) * CN + n0 + x];
  __syncthreads();
  #pragma unroll
  for (int i = 0; i < 4; ++i)
    dst[(size_t)(n0 + y + 8 * i) * R + c0 + x] = f2bf(tile[x][y + 8 * i]);
}

// ---------------- LayerNorm (pre-attention only): 4 tokens/block, bf16 out ----------------
__global__ __launch_bounds__(256) void ln_kernel(const float* __restrict__ x,
    const float* __restrict__ g, const float* __restrict__ bta,
    unsigned short* __restrict__ out) {
  int t = blockIdx.x * 4 + (threadIdx.x >> 6);
  int lane = threadIdx.x & 63;
  const float* row = x + (size_t)t * C;
  float v[6];
  float s = 0.f, ss = 0.f;
  #pragma unroll
  for (int i = 0; i < 6; ++i) {
    v[i] = row[lane + i * 64];
    s += v[i];
    ss += v[i] * v[i];
  }
  #pragma unroll
  for (int m = 32; m >= 1; m >>= 1) {
    s += __shfl_xor(s, m);
    ss += __shfl_xor(ss, m);
  }
  float mu = s / C;
  float var = ss / C - mu * mu;
  float rstd = rsqrtf(var + 1e-5f);
  unsigned short* orow = out + (size_t)t * C;
  #pragma unroll
  for (int i = 0; i < 6; ++i) {
    int c = lane + i * 64;
    orow[c] = f2bf((v[i] - mu) * rstd * g[c] + bta[c]);
  }
}

// ------------- m97-style MFMA GEMM: A[16384 x K] @ Wt[N][K], tile MTx128 -------------
// MT=256: 512 thr / 8 waves (4x2); MT=128/64: 256 thr / 4 waves. BK=64.
// Single-buffered {barrier; stage; barrier; compute} (best measured structure).
// LDS linear (global_load_lds dest); XOR swizzle via pre-swizzled global src +
// swizzled ds_read (rule #21). T1 XCD m-swizzle.
// EPI: 0=qkv scatter bf16 (outb=q, outb2=k, outb3=v^T)
//      2=mlp1(+bias,relu->bf16)  3=mlp2(+resid+bias->f32)
template<int EPI, int MT>
__global__ __launch_bounds__(MT >= 256 ? 512 : 256) void gemm_kernel(
    const unsigned short* __restrict__ A, const unsigned short* __restrict__ Wt,
    const float* __restrict__ bias, const float* __restrict__ resid,
    float* __restrict__ outf,
    unsigned short* __restrict__ outb, unsigned short* __restrict__ outb2,
    unsigned short* __restrict__ outb3, int K, int N) {
  __shared__ unsigned short Ash[MT * 64];
  __shared__ unsigned short Bsh[128 * 64];
  constexpr int NW = (MT >= 256) ? 8 : 4;   // waves
  constexpr int WM = NW / 2;                // wave rows
  constexpr int MR = MT / WM / 16;          // M-frags per wave
  constexpr int NA = (MT / 8) / NW;         // A 1KB-windows per wave
  constexpr int NB = 16 / NW;               // B windows per wave
  int tid = threadIdx.x, lane = tid & 63, w = tid >> 6;
  int wm = w >> 1, wn = w & 1;
  int bxs = ((blockIdx.x & 7) * (gridDim.x >> 3)) + (blockIdx.x >> 3);  // T1 swizzle
  int m0 = bxs * MT, n0 = blockIdx.y * 128;
  int lrow = lane >> 3;                    // row within 8-row window
  int lchunk = (lane & 7) ^ (lrow & 7);    // pre-swizzled global 16B-chunk
  int frow = lane & 15, cg = lane >> 4;
  float4v acc[MR][4] = {};
  for (int k0 = 0; k0 < K; k0 += 64) {
    __syncthreads();
    #pragma unroll
    for (int i = 0; i < NA; ++i) {
      int win = w * NA + i;
      gld16(A + (size_t)(m0 + win * 8 + lrow) * K + k0 + lchunk * 8, &Ash[win * 512]);
    }
    #pragma unroll
    for (int i = 0; i < NB; ++i) {
      int win = w * NB + i;
      gld16(Wt + (size_t)(n0 + win * 8 + lrow) * K + k0 + lchunk * 8, &Bsh[win * 512]);
    }
    __syncthreads();
    #pragma unroll
    for (int ks = 0; ks < 2; ++ks) {
      short8 af[MR], bf[4];
      #pragma unroll
      for (int mi = 0; mi < MR; ++mi) {
        int r = wm * (MR * 16) + mi * 16 + frow;
        int ch = (ks * 4 + cg) ^ (r & 7);
        af[mi] = *(const short8*)((const char*)Ash + r * 128 + ch * 16);
      }
      #pragma unroll
      for (int ni = 0; ni < 4; ++ni) {
        int r = wn * 64 + ni * 16 + frow;
        int ch = (ks * 4 + cg) ^ (r & 7);
        bf[ni] = *(const short8*)((const char*)Bsh + r * 128 + ch * 16);
      }
      #pragma unroll
      for (int mi = 0; mi < MR; ++mi)
        #pragma unroll
        for (int ni = 0; ni < 4; ++ni)
          acc[mi][ni] = __builtin_amdgcn_mfma_f32_16x16x32_bf16(af[mi], bf[ni], acc[mi][ni], 0, 0, 0);
    }
  }
  int cl = lane & 15;
  #pragma unroll
  for (int mi = 0; mi < MR; ++mi) {
    #pragma unroll
    for (int ni = 0; ni < 4; ++ni) {
      if constexpr (EPI == 0) {
        int gc = n0 + wn * 64 + ni * 16 + cl;
        int mat = gc / 384;
        int head = (gc % 384) >> 6;
        int hs = gc & 63;
        int gr0 = m0 + wm * (MR * 16) + mi * 16 + cg * 4;
        int tt0 = gr0 & 255, bidx = gr0 >> 8;
        size_t bhb = (size_t)(bidx * H + head);
        if (mat == 2) {
          ushort4v pk;
          #pragma unroll
          for (int j = 0; j < 4; ++j) pk[j] = f2bf(acc[mi][ni][j]);
          *(ushort4v*)&outb3[(bhb * HS + hs) * T + tt0] = pk;
        } else {
          unsigned short* dst = (mat == 0) ? outb : outb2;
          #pragma unroll
          for (int j = 0; j < 4; ++j)
            dst[(bhb * T + tt0 + j) * HS + hs] = f2bf(acc[mi][ni][j]);
        }
      } else {
        #pragma unroll
        for (int j = 0; j < 4; ++j) {
          int gr = m0 + wm * (MR * 16) + mi * 16 + cg * 4 + j;
          int gc = n0 + wn * 64 + ni * 16 + cl;
          float val = acc[mi][ni][j];
          if constexpr (EPI == 2) {
            outb[(size_t)gr * N + gc] = f2bf(fmaxf(val + bias[gc], 0.f));
          } else {
            size_t i = (size_t)gr * N + gc;
            outf[i] = resid[i] + val + bias[gc];
          }
        }
      }
    }
  }
}

// ------- fused proj + residual + LayerNorm2: x2 = x + attn@Wo + bo; h2 = LN(x2) -------
// MT=32, NT=384, 512 thr / 8 waves (2M x 4N), wave tile 16x96 (6 frags).
// Grid 512 = 2 blocks/CU (53KB LDS) -> cross-block overlap of stage drains.
__global__ __launch_bounds__(512) void proj_ln_kernel(
    const unsigned short* __restrict__ A, const unsigned short* __restrict__ Wt,
    const float* __restrict__ bo, const float* __restrict__ x,
    const float* __restrict__ g2, const float* __restrict__ be2,
    float* __restrict__ x2, unsigned short* __restrict__ h2) {
  __shared__ unsigned short Ash[32 * 64];    // 4KB
  __shared__ unsigned short Bsh[384 * 64];   // 48KB
  __shared__ float red[32][4][2];            // [row][wn][{s,ss}]
  int tid = threadIdx.x, lane = tid & 63, w = tid >> 6;
  int wm = w >> 2, wn = w & 3;
  int bxs = ((blockIdx.x & 7) * (gridDim.x >> 3)) + (blockIdx.x >> 3);
  int m0 = bxs * 32;
  int lrow = lane >> 3;
  int lchunk = (lane & 7) ^ (lrow & 7);
  int frow = lane & 15, cg = lane >> 4, cl = lane & 15;
  float4v acc[6] = {};
  for (int k0 = 0; k0 < 384; k0 += 64) {
    __syncthreads();
    if (w < 4) gld16(A + (size_t)(m0 + w * 8 + lrow) * 384 + k0 + lchunk * 8, &Ash[w * 512]);
    #pragma unroll
    for (int i = 0; i < 6; ++i) {
      int win = w * 6 + i;
      gld16(Wt + (size_t)(win * 8 + lrow) * 384 + k0 + lchunk * 8, &Bsh[win * 512]);
    }
    __syncthreads();
    #pragma unroll
    for (int ks = 0; ks < 2; ++ks) {
      int ra = wm * 16 + frow;
      int cha = (ks * 4 + cg) ^ (ra & 7);
      short8 af = *(const short8*)((const char*)Ash + ra * 128 + cha * 16);
      #pragma unroll
      for (int nt = 0; nt < 6; ++nt) {
        int rb = wn * 96 + nt * 16 + frow;
        int chb = (ks * 4 + cg) ^ (rb & 7);
        short8 bf = *(const short8*)((const char*)Bsh + rb * 128 + chb * 16);
        acc[nt] = __builtin_amdgcn_mfma_f32_16x16x32_bf16(af, bf, acc[nt], 0, 0, 0);
      }
    }
  }
  #pragma unroll
  for (int nt = 0; nt < 6; ++nt) {
    int gc = wn * 96 + nt * 16 + cl;
    #pragma unroll
    for (int j = 0; j < 4; ++j) {
      int gr = m0 + wm * 16 + cg * 4 + j;
      acc[nt][j] += x[(size_t)gr * 384 + gc] + bo[gc];
    }
  }
  __syncthreads();
  #pragma unroll
  for (int j = 0; j < 4; ++j) {
    float s = 0.f, ss = 0.f;
    #pragma unroll
    for (int nt = 0; nt < 6; ++nt) { float v = acc[nt][j]; s += v; ss += v * v; }
    #pragma unroll
    for (int off = 1; off < 16; off <<= 1) { s += __shfl_xor(s, off); ss += __shfl_xor(ss, off); }
    if (cl == 0) {
      int lr = wm * 16 + cg * 4 + j;
      red[lr][wn][0] = s;
      red[lr][wn][1] = ss;
    }
  }
  __syncthreads();
  #pragma unroll
  for (int j = 0; j < 4; ++j) {
    int lr = wm * 16 + cg * 4 + j;
    int gr = m0 + lr;
    float s = red[lr][0][0] + red[lr][1][0] + red[lr][2][0] + red[lr][3][0];
    float ss = red[lr][0][1] + red[lr][1][1] + red[lr][2][1] + red[lr][3][1];
    float mu = s / 384.f;
    float var = ss / 384.f - mu * mu;
    float rstd = rsqrtf(var + 1e-5f);
    #pragma unroll
    for (int nt = 0; nt < 6; ++nt) {
      int gc = wn * 96 + nt * 16 + cl;
      float v = acc[nt][j];
      x2[(size_t)gr * 384 + gc] = v;
      h2[(size_t)gr * 384 + gc] = f2bf((v - mu) * rstd * g2[gc] + be2[gc]);
    }
  }
}

// ------- MFMA attention: 1-D grid with qt interleave (load-balance tail fix) -------
// bid = bh*4 + qt with qt FASTEST -> heavy (qt=3) and light (qt=0) blocks are
// uniformly interleaved in dispatch order instead of all-heavy-last.
// q,k: bf16 [bh][t][hs]; v: bf16 [bh][hs][t] (pre-transposed)
__global__ __launch_bounds__(256) void attn_kernel(
    const unsigned short* __restrict__ qg, const unsigned short* __restrict__ kg,
    const unsigned short* __restrict__ vtg, unsigned short* __restrict__ ab) {
  __shared__ unsigned short Ksh[64 * 64];    // [s][hs], XOR-swizzled
  __shared__ unsigned short Vsh[64 * 256];   // [hs][s], XOR-swizzled
  __shared__ unsigned short Psh[4 * 16 * 256];  // per-wave [16 q][256 s], swizzled
  int bh = blockIdx.x >> 2;
  int qt = blockIdx.x & 3;
  int bb = bh / H, hh = bh % H;
  int q0 = qt * 64;
  int tid = threadIdx.x, lane = tid & 63, w = tid >> 6;
  int cl = lane & 15, cg = lane >> 4;
  const float scale_log2e = 0.125f * 1.44269504f;
  const unsigned short* qp = qg + ((size_t)bh * T) * HS;
  const unsigned short* kp = kg + ((size_t)bh * T) * HS;
  const unsigned short* vp = vtg + ((size_t)bh * HS) * T;

  short8 aq[2];
  #pragma unroll
  for (int k0 = 0; k0 < 2; ++k0)
    aq[k0] = *(const short8*)&qp[(size_t)(q0 + w * 16 + cl) * HS + cg * 8 + k0 * 32];

  #pragma unroll
  for (int i = 0; i < 8; ++i) {
    int idx = tid + i * 256;
    int r = idx >> 5, c16 = idx & 31;
    uint4 val = *(const uint4*)&vp[(size_t)r * T + c16 * 8];
    int byte = (r * 512 + c16 * 16) ^ ((r & 7) << 4);
    *(uint4*)((char*)Vsh + byte) = val;
  }

  float4v sacc[4][4] = {};
  for (int si = 0; si <= qt; ++si) {
    __syncthreads();
    #pragma unroll
    for (int i = 0; i < 2; ++i) {
      int idx = tid + i * 256;
      int r = idx >> 3, c16 = idx & 7;
      uint4 val = *(const uint4*)&kp[(size_t)(si * 64 + r) * HS + c16 * 8];
      int byte = (r * 128 + c16 * 16) ^ ((r & 7) << 4);
      *(uint4*)((char*)Ksh + byte) = val;
    }
    __syncthreads();
    #pragma unroll
    for (int ss = 0; ss < 4; ++ss) {
      if (ss == si) {
        #pragma unroll
        for (int nt = 0; nt < 4; ++nt) {
          int srow = nt * 16 + cl;
          #pragma unroll
          for (int k0 = 0; k0 < 2; ++k0) {
            int byte = (srow * 128 + (cg * 8 + k0 * 32) * 2) ^ ((srow & 7) << 4);
            short8 bf = *(const short8*)((char*)Ksh + byte);
            sacc[ss][nt] = __builtin_amdgcn_mfma_f32_16x16x32_bf16(aq[k0], bf, sacc[ss][nt], 0, 0, 0);
          }
        }
      }
    }
  }

  #pragma unroll
  for (int si = 0; si < 4; ++si) {
    if (si == qt) {
      #pragma unroll
      for (int nt = 0; nt < 4; ++nt) {
        int s = q0 + nt * 16 + cl;
        #pragma unroll
        for (int j = 0; j < 4; ++j) {
          int q = q0 + w * 16 + cg * 4 + j;
          if (s > q) sacc[si][nt][j] = -1e30f;
        }
      }
    }
  }

  float lj[4];
  #pragma unroll
  for (int j = 0; j < 4; ++j) {
    float m = -1e30f;
    #pragma unroll
    for (int si = 0; si < 4; ++si) if (si <= qt)
      #pragma unroll
      for (int nt = 0; nt < 4; ++nt) m = fmaxf(m, sacc[si][nt][j]);
    #pragma unroll
    for (int off = 1; off < 16; off <<= 1) m = fmaxf(m, __shfl_xor(m, off));
    float l = 0.f;
    #pragma unroll
    for (int si = 0; si < 4; ++si) if (si <= qt)
      #pragma unroll
      for (int nt = 0; nt < 4; ++nt) {
        float p0 = exp2f((sacc[si][nt][j] - m) * scale_log2e);
        sacc[si][nt][j] = p0;
        l += p0;
      }
    #pragma unroll
    for (int off = 1; off < 16; off <<= 1) l += __shfl_xor(l, off);
    lj[j] = 1.f / l;
  }

  char* pbase = (char*)Psh + w * 8192;
  #pragma unroll
  for (int si = 0; si < 4; ++si) if (si <= qt)
    #pragma unroll
    for (int nt = 0; nt < 4; ++nt)
      #pragma unroll
      for (int j = 0; j < 4; ++j) {
        int prow = cg * 4 + j, col = si * 64 + nt * 16 + cl;
        int byte = (prow * 512 + col * 2) ^ ((prow & 7) << 4);
        *(unsigned short*)(pbase + byte) = f2bf(sacc[si][nt][j]);
      }

  int nks = 2 * (qt + 1);
  #pragma unroll
  for (int nt = 0; nt < 4; ++nt) {
    float4v oacc = {};
    for (int ks = 0; ks < nks; ++ks) {
      int k = ks * 32 + cg * 8;
      int pbyte = (cl * 512 + k * 2) ^ ((cl & 7) << 4);
      short8 af = *(const short8*)(pbase + pbyte);
      int vr = nt * 16 + cl;
      int vbyte = (vr * 512 + k * 2) ^ ((vr & 7) << 4);
      short8 bf = *(const short8*)((char*)Vsh + vbyte);
      oacc = __builtin_amdgcn_mfma_f32_16x16x32_bf16(af, bf, oacc, 0, 0, 0);
    }
    #pragma unroll
    for (int j = 0; j < 4; ++j) {
      int t = q0 + w * 16 + cg * 4 + j;
      ab[((size_t)(bb * T + t)) * C + hh * 64 + nt * 16 + cl] = f2bf(oacc[j] * lj[j]);
    }
  }
}

extern "C" void kernel_launch(void* const* d_in, const int* in_sizes, int n_in,
                              void* d_out, int out_size, void* d_ws, size_t ws_size,
                              hipStream_t stream) {
  const float* x   = (const float*)d_in[0];
  const float* Wq  = (const float*)d_in[1];
  const float* Wk  = (const float*)d_in[2];
  const float* Wv  = (const float*)d_in[3];
  const float* Wo  = (const float*)d_in[4];
  const float* bo  = (const float*)d_in[5];
  const float* W1  = (const float*)d_in[6];
  const float* b1  = (const float*)d_in[7];
  const float* W2  = (const float*)d_in[8];
  const float* b2  = (const float*)d_in[9];
  const float* g1  = (const float*)d_in[10];
  const float* be1 = (const float*)d_in[11];
  const float* g2  = (const float*)d_in[12];
  const float* be2 = (const float*)d_in[13];
  float* out = (float*)d_out;
  float* ws = (float*)d_ws;

  // workspace layout (float units)
  unsigned short* wqkv_t = (unsigned short*)ws;          // 442368 sh
  unsigned short* wo_t   = wqkv_t + 442368;              // 147456 sh
  unsigned short* w1t    = wo_t + 147456;                // 589824 sh
  unsigned short* w2t    = w1t + 589824;                 // 589824 sh (tot 884736 fl)
  float* base2 = ws + 884736;
  unsigned short* h  = (unsigned short*)base2;           // 3145728 fl
  float* x2 = base2 + 3145728;                           // 6291456 fl
  unsigned short* ab = (unsigned short*)(x2 + 6291456);  // 3145728 fl
  unsigned short* qb = (unsigned short*)(x2 + 6291456 + 3145728);      // 3145728 fl
  unsigned short* kb = qb + 6291456;                     // 3145728 fl
  unsigned short* vt = kb + 6291456;                     // 3145728 fl
  unsigned short* ffb = ab;                              // reuses ab.. (12.58M fl)

  prep_w<<<1728, 256, 0, stream>>>(Wq, Wk, Wv, Wo, W1, W2, wqkv_t, wo_t, w1t, w2t);
  ln_kernel<<<BT / 4, 256, 0, stream>>>(x, g1, be1, h);
  gemm_kernel<0, 256><<<dim3(64, 9), 512, 0, stream>>>(h, wqkv_t, nullptr, nullptr,
                                                       nullptr, qb, kb, vt, 384, 1152);
  attn_kernel<<<B * H * 4, 256, 0, stream>>>(qb, kb, vt, ab);
  proj_ln_kernel<<<512, 512, 0, stream>>>(ab, wo_t, bo, x, g2, be2, x2, h);
  gemm_kernel<2, 256><<<dim3(64, 12), 512, 0, stream>>>(h, w1t, b1, nullptr,
                                                        nullptr, ffb, nullptr, nullptr, 384, 1536);
  gemm_kernel<3, 64><<<dim3(256, 3), 256, 0, stream>>>(ffb, w2t, b2, x2,
                                                       out, nullptr, nullptr, nullptr, 1536, 384);
}

// Round 17
// 153.435 us; speedup vs baseline: 1.0217x; 1.0217x over previous
//
#include <hip/hip_runtime.h>

#define B 64
#define T 256
#define C 384
#define H 6
#define HS 64
#define DFF 1536
#define BT (B*T)

typedef __attribute__((ext_vector_type(8))) short short8;
typedef __attribute__((ext_vector_type(4))) float float4v;
typedef __attribute__((ext_vector_type(4))) unsigned short ushort4v;

static __device__ __forceinline__ unsigned short f2bf(float f) {
  unsigned int u = __float_as_uint(f);
  unsigned int r = (u + 0x7fffu + ((u >> 16) & 1u)) >> 16;
  return (unsigned short)r;
}

typedef __attribute__((address_space(1))) const unsigned int ga_u32;
typedef __attribute__((address_space(3))) unsigned int ls_u32;
static __device__ __forceinline__ void gld16(const void* g, void* l) {
  __builtin_amdgcn_global_load_lds((ga_u32*)g, (ls_u32*)l, 16, 0, 0);
}

// ---------------- weight prep: transpose + f32->bf16 ----------------
__global__ __launch_bounds__(256) void prep_w(
    const float* __restrict__ Wq, const float* __restrict__ Wk, const float* __restrict__ Wv,
    const float* __restrict__ Wo, const float* __restrict__ W1, const float* __restrict__ W2,
    unsigned short* __restrict__ wqkv, unsigned short* __restrict__ wo,
    unsigned short* __restrict__ w1t, unsigned short* __restrict__ w2t) {
  __shared__ float tile[32][33];
  int bx = blockIdx.x;
  int x = threadIdx.x & 31, y = threadIdx.x >> 5;
  if (bx < 432) {  // QKV -> wqkv[1152][384]
    int tn = bx % 36, tc = bx / 36;
    int n0 = tn * 32, c0 = tc * 32;
    int mat = n0 / 384, rem = n0 % 384, head = rem / 64, hs0 = rem % 64;
    const float* W = (mat == 0) ? Wq : ((mat == 1) ? Wk : Wv);
    const float* src = W + (size_t)head * C * HS + hs0;
    #pragma unroll
    for (int i = 0; i < 4; ++i) tile[y + 8 * i][x] = src[(size_t)(c0 + y + 8 * i) * 64 + x];
    __syncthreads();
    #pragma unroll
    for (int i = 0; i < 4; ++i)
      wqkv[(size_t)(n0 + y + 8 * i) * 384 + c0 + x] = f2bf(tile[x][y + 8 * i]);
    return;
  }
  const float* src; unsigned short* dst; int CN, R, n0, c0;
  if (bx < 576) {         // Wo [384][384]
    int t = bx - 432; n0 = (t % 12) * 32; c0 = (t / 12) * 32;
    src = Wo; dst = wo; CN = 384; R = 384;
  } else if (bx < 1152) { // W1 [384][1536]
    int t = bx - 576; n0 = (t % 48) * 32; c0 = (t / 48) * 32;
    src = W1; dst = w1t; CN = 1536; R = 384;
  } else {                // W2 [1536][384]
    int t = bx - 1152; n0 = (t % 12) * 32; c0 = (t / 12) * 32;
    src = W2; dst = w2t; CN = 384; R = 1536;
  }
  #pragma unroll
  for (int i = 0; i < 4; ++i) tile[y + 8 * i][x] = src[(size_t)(c0 + y + 8 * i) * CN + n0 + x];
  __syncthreads();
  #pragma unroll
  for (int i = 0; i < 4; ++i)
    dst[(size_t)(n0 + y + 8 * i) * R + c0 + x] = f2bf(tile[x][y + 8 * i]);
}

// ---------------- LayerNorm (pre-attention only): 4 tokens/block, bf16 out ----------------
__global__ __launch_bounds__(256) void ln_kernel(const float* __restrict__ x,
    const float* __restrict__ g, const float* __restrict__ bta,
    unsigned short* __restrict__ out) {
  int t = blockIdx.x * 4 + (threadIdx.x >> 6);
  int lane = threadIdx.x & 63;
  const float* row = x + (size_t)t * C;
  float v[6];
  float s = 0.f, ss = 0.f;
  #pragma unroll
  for (int i = 0; i < 6; ++i) {
    v[i] = row[lane + i * 64];
    s += v[i];
    ss += v[i] * v[i];
  }
  #pragma unroll
  for (int m = 32; m >= 1; m >>= 1) {
    s += __shfl_xor(s, m);
    ss += __shfl_xor(ss, m);
  }
  float mu = s / C;
  float var = ss / C - mu * mu;
  float rstd = rsqrtf(var + 1e-5f);
  unsigned short* orow = out + (size_t)t * C;
  #pragma unroll
  for (int i = 0; i < 6; ++i) {
    int c = lane + i * 64;
    orow[c] = f2bf((v[i] - mu) * rstd * g[c] + bta[c]);
  }
}

// ------------- m97-style MFMA GEMM: A[16384 x K] @ Wt[N][K], tile MTx128 -------------
// MT=256: 512 thr / 8 waves (4x2); MT=128/64: 256 thr / 4 waves. BK=64.
// Single-buffered {barrier; stage; barrier; compute} (best measured structure).
// LDS linear (global_load_lds dest); XOR swizzle via pre-swizzled global src +
// swizzled ds_read (rule #21). T1 XCD m-swizzle.
// EPI: 0=qkv scatter bf16 (outb=q, outb2=k, outb3=v^T)
//      2=mlp1(+bias,relu->bf16)  3=mlp2(+resid+bias->f32)
template<int EPI, int MT>
__global__ __launch_bounds__(MT >= 256 ? 512 : 256) void gemm_kernel(
    const unsigned short* __restrict__ A, const unsigned short* __restrict__ Wt,
    const float* __restrict__ bias, const float* __restrict__ resid,
    float* __restrict__ outf,
    unsigned short* __restrict__ outb, unsigned short* __restrict__ outb2,
    unsigned short* __restrict__ outb3, int K, int N) {
  __shared__ unsigned short Ash[MT * 64];
  __shared__ unsigned short Bsh[128 * 64];
  constexpr int NW = (MT >= 256) ? 8 : 4;   // waves
  constexpr int WM = NW / 2;                // wave rows
  constexpr int MR = MT / WM / 16;          // M-frags per wave
  constexpr int NA = (MT / 8) / NW;         // A 1KB-windows per wave
  constexpr int NB = 16 / NW;               // B windows per wave
  int tid = threadIdx.x, lane = tid & 63, w = tid >> 6;
  int wm = w >> 1, wn = w & 1;
  int bxs = ((blockIdx.x & 7) * (gridDim.x >> 3)) + (blockIdx.x >> 3);  // T1 swizzle
  int m0 = bxs * MT, n0 = blockIdx.y * 128;
  int lrow = lane >> 3;                    // row within 8-row window
  int lchunk = (lane & 7) ^ (lrow & 7);    // pre-swizzled global 16B-chunk
  int frow = lane & 15, cg = lane >> 4;
  float4v acc[MR][4] = {};
  for (int k0 = 0; k0 < K; k0 += 64) {
    __syncthreads();
    #pragma unroll
    for (int i = 0; i < NA; ++i) {
      int win = w * NA + i;
      gld16(A + (size_t)(m0 + win * 8 + lrow) * K + k0 + lchunk * 8, &Ash[win * 512]);
    }
    #pragma unroll
    for (int i = 0; i < NB; ++i) {
      int win = w * NB + i;
      gld16(Wt + (size_t)(n0 + win * 8 + lrow) * K + k0 + lchunk * 8, &Bsh[win * 512]);
    }
    __syncthreads();
    #pragma unroll
    for (int ks = 0; ks < 2; ++ks) {
      short8 af[MR], bf[4];
      #pragma unroll
      for (int mi = 0; mi < MR; ++mi) {
        int r = wm * (MR * 16) + mi * 16 + frow;
        int ch = (ks * 4 + cg) ^ (r & 7);
        af[mi] = *(const short8*)((const char*)Ash + r * 128 + ch * 16);
      }
      #pragma unroll
      for (int ni = 0; ni < 4; ++ni) {
        int r = wn * 64 + ni * 16 + frow;
        int ch = (ks * 4 + cg) ^ (r & 7);
        bf[ni] = *(const short8*)((const char*)Bsh + r * 128 + ch * 16);
      }
      #pragma unroll
      for (int mi = 0; mi < MR; ++mi)
        #pragma unroll
        for (int ni = 0; ni < 4; ++ni)
          acc[mi][ni] = __builtin_amdgcn_mfma_f32_16x16x32_bf16(af[mi], bf[ni], acc[mi][ni], 0, 0, 0);
    }
  }
  int cl = lane & 15;
  #pragma unroll
  for (int mi = 0; mi < MR; ++mi) {
    #pragma unroll
    for (int ni = 0; ni < 4; ++ni) {
      if constexpr (EPI == 0) {
        int gc = n0 + wn * 64 + ni * 16 + cl;
        int mat = gc / 384;
        int head = (gc % 384) >> 6;
        int hs = gc & 63;
        int gr0 = m0 + wm * (MR * 16) + mi * 16 + cg * 4;
        int tt0 = gr0 & 255, bidx = gr0 >> 8;
        size_t bhb = (size_t)(bidx * H + head);
        if (mat == 2) {
          ushort4v pk;
          #pragma unroll
          for (int j = 0; j < 4; ++j) pk[j] = f2bf(acc[mi][ni][j]);
          *(ushort4v*)&outb3[(bhb * HS + hs) * T + tt0] = pk;
        } else {
          unsigned short* dst = (mat == 0) ? outb : outb2;
          #pragma unroll
          for (int j = 0; j < 4; ++j)
            dst[(bhb * T + tt0 + j) * HS + hs] = f2bf(acc[mi][ni][j]);
        }
      } else {
        #pragma unroll
        for (int j = 0; j < 4; ++j) {
          int gr = m0 + wm * (MR * 16) + mi * 16 + cg * 4 + j;
          int gc = n0 + wn * 64 + ni * 16 + cl;
          float val = acc[mi][ni][j];
          if constexpr (EPI == 2) {
            outb[(size_t)gr * N + gc] = f2bf(fmaxf(val + bias[gc], 0.f));
          } else {
            size_t i = (size_t)gr * N + gc;
            outf[i] = resid[i] + val + bias[gc];
          }
        }
      }
    }
  }
}

// ------- fused proj + residual + LayerNorm2: x2 = x + attn@Wo + bo; h2 = LN(x2) -------
// MT=32, NT=384, 512 thr / 8 waves (2M x 4N), wave tile 16x96 (6 frags).
// Grid 512 = 2 blocks/CU (53KB LDS) -> cross-block overlap of stage drains.
__global__ __launch_bounds__(512) void proj_ln_kernel(
    const unsigned short* __restrict__ A, const unsigned short* __restrict__ Wt,
    const float* __restrict__ bo, const float* __restrict__ x,
    const float* __restrict__ g2, const float* __restrict__ be2,
    float* __restrict__ x2, unsigned short* __restrict__ h2) {
  __shared__ unsigned short Ash[32 * 64];    // 4KB
  __shared__ unsigned short Bsh[384 * 64];   // 48KB
  __shared__ float red[32][4][2];            // [row][wn][{s,ss}]
  int tid = threadIdx.x, lane = tid & 63, w = tid >> 6;
  int wm = w >> 2, wn = w & 3;
  int bxs = ((blockIdx.x & 7) * (gridDim.x >> 3)) + (blockIdx.x >> 3);
  int m0 = bxs * 32;
  int lrow = lane >> 3;
  int lchunk = (lane & 7) ^ (lrow & 7);
  int frow = lane & 15, cg = lane >> 4, cl = lane & 15;
  float4v acc[6] = {};
  for (int k0 = 0; k0 < 384; k0 += 64) {
    __syncthreads();
    if (w < 4) gld16(A + (size_t)(m0 + w * 8 + lrow) * 384 + k0 + lchunk * 8, &Ash[w * 512]);
    #pragma unroll
    for (int i = 0; i < 6; ++i) {
      int win = w * 6 + i;
      gld16(Wt + (size_t)(win * 8 + lrow) * 384 + k0 + lchunk * 8, &Bsh[win * 512]);
    }
    __syncthreads();
    #pragma unroll
    for (int ks = 0; ks < 2; ++ks) {
      int ra = wm * 16 + frow;
      int cha = (ks * 4 + cg) ^ (ra & 7);
      short8 af = *(const short8*)((const char*)Ash + ra * 128 + cha * 16);
      #pragma unroll
      for (int nt = 0; nt < 6; ++nt) {
        int rb = wn * 96 + nt * 16 + frow;
        int chb = (ks * 4 + cg) ^ (rb & 7);
        short8 bf = *(const short8*)((const char*)Bsh + rb * 128 + chb * 16);
        acc[nt] = __builtin_amdgcn_mfma_f32_16x16x32_bf16(af, bf, acc[nt], 0, 0, 0);
      }
    }
  }
  #pragma unroll
  for (int nt = 0; nt < 6; ++nt) {
    int gc = wn * 96 + nt * 16 + cl;
    #pragma unroll
    for (int j = 0; j < 4; ++j) {
      int gr = m0 + wm * 16 + cg * 4 + j;
      acc[nt][j] += x[(size_t)gr * 384 + gc] + bo[gc];
    }
  }
  __syncthreads();
  #pragma unroll
  for (int j = 0; j < 4; ++j) {
    float s = 0.f, ss = 0.f;
    #pragma unroll
    for (int nt = 0; nt < 6; ++nt) { float v = acc[nt][j]; s += v; ss += v * v; }
    #pragma unroll
    for (int off = 1; off < 16; off <<= 1) { s += __shfl_xor(s, off); ss += __shfl_xor(ss, off); }
    if (cl == 0) {
      int lr = wm * 16 + cg * 4 + j;
      red[lr][wn][0] = s;
      red[lr][wn][1] = ss;
    }
  }
  __syncthreads();
  #pragma unroll
  for (int j = 0; j < 4; ++j) {
    int lr = wm * 16 + cg * 4 + j;
    int gr = m0 + lr;
    float s = red[lr][0][0] + red[lr][1][0] + red[lr][2][0] + red[lr][3][0];
    float ss = red[lr][0][1] + red[lr][1][1] + red[lr][2][1] + red[lr][3][1];
    float mu = s / 384.f;
    float var = ss / 384.f - mu * mu;
    float rstd = rsqrtf(var + 1e-5f);
    #pragma unroll
    for (int nt = 0; nt < 6; ++nt) {
      int gc = wn * 96 + nt * 16 + cl;
      float v = acc[nt][j];
      x2[(size_t)gr * 384 + gc] = v;
      h2[(size_t)gr * 384 + gc] = f2bf((v - mu) * rstd * g2[gc] + be2[gc]);
    }
  }
}

// ------- MFMA attention: XCD-affine + qt-interleaved 1-D grid -------
// bid -> x=bid&7 (XCD), i=bid>>3, qt=i&3, bh=x+8*(i>>2). Keeps every block of a
// given bh on XCD bh%8 (K/V fetched into ONE L2 — round-16 lesson: spraying qt
// across XCDs 4x'd FETCH_SIZE) while interleaving heavy/light qt in issue order.
// q,k: bf16 [bh][t][hs]; v: bf16 [bh][hs][t] (pre-transposed)
__global__ __launch_bounds__(256) void attn_kernel(
    const unsigned short* __restrict__ qg, const unsigned short* __restrict__ kg,
    const unsigned short* __restrict__ vtg, unsigned short* __restrict__ ab) {
  __shared__ unsigned short Ksh[64 * 64];    // [s][hs], XOR-swizzled
  __shared__ unsigned short Vsh[64 * 256];   // [hs][s], XOR-swizzled
  __shared__ unsigned short Psh[4 * 16 * 256];  // per-wave [16 q][256 s], swizzled
  int xcd = blockIdx.x & 7;
  int ii = blockIdx.x >> 3;
  int qt = ii & 3;
  int bh = xcd + 8 * (ii >> 2);
  int bb = bh / H, hh = bh % H;
  int q0 = qt * 64;
  int tid = threadIdx.x, lane = tid & 63, w = tid >> 6;
  int cl = lane & 15, cg = lane >> 4;
  const float scale_log2e = 0.125f * 1.44269504f;
  const unsigned short* qp = qg + ((size_t)bh * T) * HS;
  const unsigned short* kp = kg + ((size_t)bh * T) * HS;
  const unsigned short* vp = vtg + ((size_t)bh * HS) * T;

  short8 aq[2];
  #pragma unroll
  for (int k0 = 0; k0 < 2; ++k0)
    aq[k0] = *(const short8*)&qp[(size_t)(q0 + w * 16 + cl) * HS + cg * 8 + k0 * 32];

  #pragma unroll
  for (int i = 0; i < 8; ++i) {
    int idx = tid + i * 256;
    int r = idx >> 5, c16 = idx & 31;
    uint4 val = *(const uint4*)&vp[(size_t)r * T + c16 * 8];
    int byte = (r * 512 + c16 * 16) ^ ((r & 7) << 4);
    *(uint4*)((char*)Vsh + byte) = val;
  }

  float4v sacc[4][4] = {};
  for (int si = 0; si <= qt; ++si) {
    __syncthreads();
    #pragma unroll
    for (int i = 0; i < 2; ++i) {
      int idx = tid + i * 256;
      int r = idx >> 3, c16 = idx & 7;
      uint4 val = *(const uint4*)&kp[(size_t)(si * 64 + r) * HS + c16 * 8];
      int byte = (r * 128 + c16 * 16) ^ ((r & 7) << 4);
      *(uint4*)((char*)Ksh + byte) = val;
    }
    __syncthreads();
    #pragma unroll
    for (int ss = 0; ss < 4; ++ss) {
      if (ss == si) {
        #pragma unroll
        for (int nt = 0; nt < 4; ++nt) {
          int srow = nt * 16 + cl;
          #pragma unroll
          for (int k0 = 0; k0 < 2; ++k0) {
            int byte = (srow * 128 + (cg * 8 + k0 * 32) * 2) ^ ((srow & 7) << 4);
            short8 bf = *(const short8*)((char*)Ksh + byte);
            sacc[ss][nt] = __builtin_amdgcn_mfma_f32_16x16x32_bf16(aq[k0], bf, sacc[ss][nt], 0, 0, 0);
          }
        }
      }
    }
  }

  #pragma unroll
  for (int si = 0; si < 4; ++si) {
    if (si == qt) {
      #pragma unroll
      for (int nt = 0; nt < 4; ++nt) {
        int s = q0 + nt * 16 + cl;
        #pragma unroll
        for (int j = 0; j < 4; ++j) {
          int q = q0 + w * 16 + cg * 4 + j;
          if (s > q) sacc[si][nt][j] = -1e30f;
        }
      }
    }
  }

  float lj[4];
  #pragma unroll
  for (int j = 0; j < 4; ++j) {
    float m = -1e30f;
    #pragma unroll
    for (int si = 0; si < 4; ++si) if (si <= qt)
      #pragma unroll
      for (int nt = 0; nt < 4; ++nt) m = fmaxf(m, sacc[si][nt][j]);
    #pragma unroll
    for (int off = 1; off < 16; off <<= 1) m = fmaxf(m, __shfl_xor(m, off));
    float l = 0.f;
    #pragma unroll
    for (int si = 0; si < 4; ++si) if (si <= qt)
      #pragma unroll
      for (int nt = 0; nt < 4; ++nt) {
        float p0 = exp2f((sacc[si][nt][j] - m) * scale_log2e);
        sacc[si][nt][j] = p0;
        l += p0;
      }
    #pragma unroll
    for (int off = 1; off < 16; off <<= 1) l += __shfl_xor(l, off);
    lj[j] = 1.f / l;
  }

  char* pbase = (char*)Psh + w * 8192;
  #pragma unroll
  for (int si = 0; si < 4; ++si) if (si <= qt)
    #pragma unroll
    for (int nt = 0; nt < 4; ++nt)
      #pragma unroll
      for (int j = 0; j < 4; ++j) {
        int prow = cg * 4 + j, col = si * 64 + nt * 16 + cl;
        int byte = (prow * 512 + col * 2) ^ ((prow & 7) << 4);
        *(unsigned short*)(pbase + byte) = f2bf(sacc[si][nt][j]);
      }

  int nks = 2 * (qt + 1);
  #pragma unroll
  for (int nt = 0; nt < 4; ++nt) {
    float4v oacc = {};
    for (int ks = 0; ks < nks; ++ks) {
      int k = ks * 32 + cg * 8;
      int pbyte = (cl * 512 + k * 2) ^ ((cl & 7) << 4);
      short8 af = *(const short8*)(pbase + pbyte);
      int vr = nt * 16 + cl;
      int vbyte = (vr * 512 + k * 2) ^ ((vr & 7) << 4);
      short8 bf = *(const short8*)((char*)Vsh + vbyte);
      oacc = __builtin_amdgcn_mfma_f32_16x16x32_bf16(af, bf, oacc, 0, 0, 0);
    }
    #pragma unroll
    for (int j = 0; j < 4; ++j) {
      int t = q0 + w * 16 + cg * 4 + j;
      ab[((size_t)(bb * T + t)) * C + hh * 64 + nt * 16 + cl] = f2bf(oacc[j] * lj[j]);
    }
  }
}

extern "C" void kernel_launch(void* const* d_in, const int* in_sizes, int n_in,
                              void* d_out, int out_size, void* d_ws, size_t ws_size,
                              hipStream_t stream) {
  const float* x   = (const float*)d_in[0];
  const float* Wq  = (const float*)d_in[1];
  const float* Wk  = (const float*)d_in[2];
  const float* Wv  = (const float*)d_in[3];
  const float* Wo  = (const float*)d_in[4];
  const float* bo  = (const float*)d_in[5];
  const float* W1  = (const float*)d_in[6];
  const float* b1  = (const float*)d_in[7];
  const float* W2  = (const float*)d_in[8];
  const float* b2  = (const float*)d_in[9];
  const float* g1  = (const float*)d_in[10];
  const float* be1 = (const float*)d_in[11];
  const float* g2  = (const float*)d_in[12];
  const float* be2 = (const float*)d_in[13];
  float* out = (float*)d_out;
  float* ws = (float*)d_ws;

  // workspace layout (float units)
  unsigned short* wqkv_t = (unsigned short*)ws;          // 442368 sh
  unsigned short* wo_t   = wqkv_t + 442368;              // 147456 sh
  unsigned short* w1t    = wo_t + 147456;                // 589824 sh
  unsigned short* w2t    = w1t + 589824;                 // 589824 sh (tot 884736 fl)
  float* base2 = ws + 884736;
  unsigned short* h  = (unsigned short*)base2;           // 3145728 fl
  float* x2 = base2 + 3145728;                           // 6291456 fl
  unsigned short* ab = (unsigned short*)(x2 + 6291456);  // 3145728 fl
  unsigned short* qb = (unsigned short*)(x2 + 6291456 + 3145728);      // 3145728 fl
  unsigned short* kb = qb + 6291456;                     // 3145728 fl
  unsigned short* vt = kb + 6291456;                     // 3145728 fl
  unsigned short* ffb = ab;                              // reuses ab.. (12.58M fl)

  prep_w<<<1728, 256, 0, stream>>>(Wq, Wk, Wv, Wo, W1, W2, wqkv_t, wo_t, w1t, w2t);
  ln_kernel<<<BT / 4, 256, 0, stream>>>(x, g1, be1, h);
  gemm_kernel<0, 256><<<dim3(64, 9), 512, 0, stream>>>(h, wqkv_t, nullptr, nullptr,
                                                       nullptr, qb, kb, vt, 384, 1152);
  attn_kernel<<<B * H * 4, 256, 0, stream>>>(qb, kb, vt, ab);
  proj_ln_kernel<<<512, 512, 0, stream>>>(ab, wo_t, bo, x, g2, be2, x2, h);
  gemm_kernel<2, 256><<<dim3(64, 12), 512, 0, stream>>>(h, w1t, b1, nullptr,
                                                        nullptr, ffb, nullptr, nullptr, 384, 1536);
  gemm_kernel<3, 64><<<dim3(256, 3), 256, 0, stream>>>(ffb, w2t, b2, x2,
                                                       out, nullptr, nullptr, nullptr, 1536, 384);
}

// Round 18
// 149.147 us; speedup vs baseline: 1.0511x; 1.0288x over previous
//
#include <hip/hip_runtime.h>

#define B 64
#define T 256
#define C 384
#define H 6
#define HS 64
#define DFF 1536
#define BT (B*T)

typedef __attribute__((ext_vector_type(8))) short short8;
typedef __attribute__((ext_vector_type(4))) float float4v;
typedef __attribute__((ext_vector_type(4))) unsigned short ushort4v;

static __device__ __forceinline__ unsigned short f2bf(float f) {
  unsigned int u = __float_as_uint(f);
  unsigned int r = (u + 0x7fffu + ((u >> 16) & 1u)) >> 16;
  return (unsigned short)r;
}

typedef __attribute__((address_space(1))) const unsigned int ga_u32;
typedef __attribute__((address_space(3))) unsigned int ls_u32;
static __device__ __forceinline__ void gld16(const void* g, void* l) {
  __builtin_amdgcn_global_load_lds((ga_u32*)g, (ls_u32*)l, 16, 0, 0);
}

// ---------------- weight prep: transpose + f32->bf16 ----------------
__global__ __launch_bounds__(256) void prep_w(
    const float* __restrict__ Wq, const float* __restrict__ Wk, const float* __restrict__ Wv,
    const float* __restrict__ Wo, const float* __restrict__ W1, const float* __restrict__ W2,
    unsigned short* __restrict__ wqkv, unsigned short* __restrict__ wo,
    unsigned short* __restrict__ w1t, unsigned short* __restrict__ w2t) {
  __shared__ float tile[32][33];
  int bx = blockIdx.x;
  int x = threadIdx.x & 31, y = threadIdx.x >> 5;
  if (bx < 432) {  // QKV -> wqkv[1152][384]
    int tn = bx % 36, tc = bx / 36;
    int n0 = tn * 32, c0 = tc * 32;
    int mat = n0 / 384, rem = n0 % 384, head = rem / 64, hs0 = rem % 64;
    const float* W = (mat == 0) ? Wq : ((mat == 1) ? Wk : Wv);
    const float* src = W + (size_t)head * C * HS + hs0;
    #pragma unroll
    for (int i = 0; i < 4; ++i) tile[y + 8 * i][x] = src[(size_t)(c0 + y + 8 * i) * 64 + x];
    __syncthreads();
    #pragma unroll
    for (int i = 0; i < 4; ++i)
      wqkv[(size_t)(n0 + y + 8 * i) * 384 + c0 + x] = f2bf(tile[x][y + 8 * i]);
    return;
  }
  const float* src; unsigned short* dst; int CN, R, n0, c0;
  if (bx < 576) {         // Wo [384][384]
    int t = bx - 432; n0 = (t % 12) * 32; c0 = (t / 12) * 32;
    src = Wo; dst = wo; CN = 384; R = 384;
  } else if (bx < 1152) { // W1 [384][1536]
    int t = bx - 576; n0 = (t % 48) * 32; c0 = (t / 48) * 32;
    src = W1; dst = w1t; CN = 1536; R = 384;
  } else {                // W2 [1536][384]
    int t = bx - 1152; n0 = (t % 12) * 32; c0 = (t / 12) * 32;
    src = W2; dst = w2t; CN = 384; R = 1536;
  }
  #pragma unroll
  for (int i = 0; i < 4; ++i) tile[y + 8 * i][x] = src[(size_t)(c0 + y + 8 * i) * CN + n0 + x];
  __syncthreads();
  #pragma unroll
  for (int i = 0; i < 4; ++i)
    dst[(size_t)(n0 + y + 8 * i) * R + c0 + x] = f2bf(tile[x][y + 8 * i]);
}

// ---------------- LayerNorm (pre-attention only): 4 tokens/block, bf16 out ----------------
__global__ __launch_bounds__(256) void ln_kernel(const float* __restrict__ x,
    const float* __restrict__ g, const float* __restrict__ bta,
    unsigned short* __restrict__ out) {
  int t = blockIdx.x * 4 + (threadIdx.x >> 6);
  int lane = threadIdx.x & 63;
  const float* row = x + (size_t)t * C;
  float v[6];
  float s = 0.f, ss = 0.f;
  #pragma unroll
  for (int i = 0; i < 6; ++i) {
    v[i] = row[lane + i * 64];
    s += v[i];
    ss += v[i] * v[i];
  }
  #pragma unroll
  for (int m = 32; m >= 1; m >>= 1) {
    s += __shfl_xor(s, m);
    ss += __shfl_xor(ss, m);
  }
  float mu = s / C;
  float var = ss / C - mu * mu;
  float rstd = rsqrtf(var + 1e-5f);
  unsigned short* orow = out + (size_t)t * C;
  #pragma unroll
  for (int i = 0; i < 6; ++i) {
    int c = lane + i * 64;
    orow[c] = f2bf((v[i] - mu) * rstd * g[c] + bta[c]);
  }
}

// ------------- m97-style MFMA GEMM: A[16384 x K] @ Wt[N][K], tile MTx128 -------------
// MT=256: 512 thr / 8 waves (4x2); MT=128/64: 256 thr / 4 waves. BK=64.
// Single-buffered {barrier; stage; barrier; compute} (best measured structure).
// LDS linear (global_load_lds dest); XOR swizzle via pre-swizzled global src +
// swizzled ds_read (rule #21). T1 XCD m-swizzle.
// EPI: 0=qkv scatter bf16 (outb=q, outb2=k, outb3=v^T)
//      2=mlp1(+bias,relu->bf16)  3=mlp2(+resid+bias->f32)
template<int EPI, int MT>
__global__ __launch_bounds__(MT >= 256 ? 512 : 256) void gemm_kernel(
    const unsigned short* __restrict__ A, const unsigned short* __restrict__ Wt,
    const float* __restrict__ bias, const float* __restrict__ resid,
    float* __restrict__ outf,
    unsigned short* __restrict__ outb, unsigned short* __restrict__ outb2,
    unsigned short* __restrict__ outb3, int K, int N) {
  __shared__ unsigned short Ash[MT * 64];
  __shared__ unsigned short Bsh[128 * 64];
  constexpr int NW = (MT >= 256) ? 8 : 4;   // waves
  constexpr int WM = NW / 2;                // wave rows
  constexpr int MR = MT / WM / 16;          // M-frags per wave
  constexpr int NA = (MT / 8) / NW;         // A 1KB-windows per wave
  constexpr int NB = 16 / NW;               // B windows per wave
  int tid = threadIdx.x, lane = tid & 63, w = tid >> 6;
  int wm = w >> 1, wn = w & 1;
  int bxs = ((blockIdx.x & 7) * (gridDim.x >> 3)) + (blockIdx.x >> 3);  // T1 swizzle
  int m0 = bxs * MT, n0 = blockIdx.y * 128;
  int lrow = lane >> 3;                    // row within 8-row window
  int lchunk = (lane & 7) ^ (lrow & 7);    // pre-swizzled global 16B-chunk
  int frow = lane & 15, cg = lane >> 4;
  float4v acc[MR][4] = {};
  for (int k0 = 0; k0 < K; k0 += 64) {
    __syncthreads();
    #pragma unroll
    for (int i = 0; i < NA; ++i) {
      int win = w * NA + i;
      gld16(A + (size_t)(m0 + win * 8 + lrow) * K + k0 + lchunk * 8, &Ash[win * 512]);
    }
    #pragma unroll
    for (int i = 0; i < NB; ++i) {
      int win = w * NB + i;
      gld16(Wt + (size_t)(n0 + win * 8 + lrow) * K + k0 + lchunk * 8, &Bsh[win * 512]);
    }
    __syncthreads();
    #pragma unroll
    for (int ks = 0; ks < 2; ++ks) {
      short8 af[MR], bf[4];
      #pragma unroll
      for (int mi = 0; mi < MR; ++mi) {
        int r = wm * (MR * 16) + mi * 16 + frow;
        int ch = (ks * 4 + cg) ^ (r & 7);
        af[mi] = *(const short8*)((const char*)Ash + r * 128 + ch * 16);
      }
      #pragma unroll
      for (int ni = 0; ni < 4; ++ni) {
        int r = wn * 64 + ni * 16 + frow;
        int ch = (ks * 4 + cg) ^ (r & 7);
        bf[ni] = *(const short8*)((const char*)Bsh + r * 128 + ch * 16);
      }
      #pragma unroll
      for (int mi = 0; mi < MR; ++mi)
        #pragma unroll
        for (int ni = 0; ni < 4; ++ni)
          acc[mi][ni] = __builtin_amdgcn_mfma_f32_16x16x32_bf16(af[mi], bf[ni], acc[mi][ni], 0, 0, 0);
    }
  }
  int cl = lane & 15;
  #pragma unroll
  for (int mi = 0; mi < MR; ++mi) {
    #pragma unroll
    for (int ni = 0; ni < 4; ++ni) {
      if constexpr (EPI == 0) {
        int gc = n0 + wn * 64 + ni * 16 + cl;
        int mat = gc / 384;
        int head = (gc % 384) >> 6;
        int hs = gc & 63;
        int gr0 = m0 + wm * (MR * 16) + mi * 16 + cg * 4;
        int tt0 = gr0 & 255, bidx = gr0 >> 8;
        size_t bhb = (size_t)(bidx * H + head);
        if (mat == 2) {
          ushort4v pk;
          #pragma unroll
          for (int j = 0; j < 4; ++j) pk[j] = f2bf(acc[mi][ni][j]);
          *(ushort4v*)&outb3[(bhb * HS + hs) * T + tt0] = pk;
        } else {
          unsigned short* dst = (mat == 0) ? outb : outb2;
          #pragma unroll
          for (int j = 0; j < 4; ++j)
            dst[(bhb * T + tt0 + j) * HS + hs] = f2bf(acc[mi][ni][j]);
        }
      } else {
        #pragma unroll
        for (int j = 0; j < 4; ++j) {
          int gr = m0 + wm * (MR * 16) + mi * 16 + cg * 4 + j;
          int gc = n0 + wn * 64 + ni * 16 + cl;
          float val = acc[mi][ni][j];
          if constexpr (EPI == 2) {
            outb[(size_t)gr * N + gc] = f2bf(fmaxf(val + bias[gc], 0.f));
          } else {
            size_t i = (size_t)gr * N + gc;
            outf[i] = resid[i] + val + bias[gc];
          }
        }
      }
    }
  }
}

// ------- fused proj + residual + LayerNorm2: x2 = x + attn@Wo + bo; h2 = LN(x2) -------
// MT=32, NT=384, 512 thr / 8 waves (2M x 4N), wave tile 16x96 (6 frags).
// Grid 512 = 2 blocks/CU (53KB LDS) -> cross-block overlap of stage drains.
__global__ __launch_bounds__(512) void proj_ln_kernel(
    const unsigned short* __restrict__ A, const unsigned short* __restrict__ Wt,
    const float* __restrict__ bo, const float* __restrict__ x,
    const float* __restrict__ g2, const float* __restrict__ be2,
    float* __restrict__ x2, unsigned short* __restrict__ h2) {
  __shared__ unsigned short Ash[32 * 64];    // 4KB
  __shared__ unsigned short Bsh[384 * 64];   // 48KB
  __shared__ float red[32][4][2];            // [row][wn][{s,ss}]
  int tid = threadIdx.x, lane = tid & 63, w = tid >> 6;
  int wm = w >> 2, wn = w & 3;
  int bxs = ((blockIdx.x & 7) * (gridDim.x >> 3)) + (blockIdx.x >> 3);
  int m0 = bxs * 32;
  int lrow = lane >> 3;
  int lchunk = (lane & 7) ^ (lrow & 7);
  int frow = lane & 15, cg = lane >> 4, cl = lane & 15;
  float4v acc[6] = {};
  for (int k0 = 0; k0 < 384; k0 += 64) {
    __syncthreads();
    if (w < 4) gld16(A + (size_t)(m0 + w * 8 + lrow) * 384 + k0 + lchunk * 8, &Ash[w * 512]);
    #pragma unroll
    for (int i = 0; i < 6; ++i) {
      int win = w * 6 + i;
      gld16(Wt + (size_t)(win * 8 + lrow) * 384 + k0 + lchunk * 8, &Bsh[win * 512]);
    }
    __syncthreads();
    #pragma unroll
    for (int ks = 0; ks < 2; ++ks) {
      int ra = wm * 16 + frow;
      int cha = (ks * 4 + cg) ^ (ra & 7);
      short8 af = *(const short8*)((const char*)Ash + ra * 128 + cha * 16);
      #pragma unroll
      for (int nt = 0; nt < 6; ++nt) {
        int rb = wn * 96 + nt * 16 + frow;
        int chb = (ks * 4 + cg) ^ (rb & 7);
        short8 bf = *(const short8*)((const char*)Bsh + rb * 128 + chb * 16);
        acc[nt] = __builtin_amdgcn_mfma_f32_16x16x32_bf16(af, bf, acc[nt], 0, 0, 0);
      }
    }
  }
  #pragma unroll
  for (int nt = 0; nt < 6; ++nt) {
    int gc = wn * 96 + nt * 16 + cl;
    #pragma unroll
    for (int j = 0; j < 4; ++j) {
      int gr = m0 + wm * 16 + cg * 4 + j;
      acc[nt][j] += x[(size_t)gr * 384 + gc] + bo[gc];
    }
  }
  __syncthreads();
  #pragma unroll
  for (int j = 0; j < 4; ++j) {
    float s = 0.f, ss = 0.f;
    #pragma unroll
    for (int nt = 0; nt < 6; ++nt) { float v = acc[nt][j]; s += v; ss += v * v; }
    #pragma unroll
    for (int off = 1; off < 16; off <<= 1) { s += __shfl_xor(s, off); ss += __shfl_xor(ss, off); }
    if (cl == 0) {
      int lr = wm * 16 + cg * 4 + j;
      red[lr][wn][0] = s;
      red[lr][wn][1] = ss;
    }
  }
  __syncthreads();
  #pragma unroll
  for (int j = 0; j < 4; ++j) {
    int lr = wm * 16 + cg * 4 + j;
    int gr = m0 + lr;
    float s = red[lr][0][0] + red[lr][1][0] + red[lr][2][0] + red[lr][3][0];
    float ss = red[lr][0][1] + red[lr][1][1] + red[lr][2][1] + red[lr][3][1];
    float mu = s / 384.f;
    float var = ss / 384.f - mu * mu;
    float rstd = rsqrtf(var + 1e-5f);
    #pragma unroll
    for (int nt = 0; nt < 6; ++nt) {
      int gc = wn * 96 + nt * 16 + cl;
      float v = acc[nt][j];
      x2[(size_t)gr * 384 + gc] = v;
      h2[(size_t)gr * 384 + gc] = f2bf((v - mu) * rstd * g2[gc] + be2[gc]);
    }
  }
}

// ------- MFMA attention: block = (b,h, 64-query tile), 4 waves (staged) -------
// q,k: bf16 [bh][t][hs]; v: bf16 [bh][hs][t] (pre-transposed)
// 2-D grid (384,4): blockIdx.x fastest keeps natural XCD affinity (384%8==0);
// measured best vs both 1-D interleave variants (rounds 15-17).
__global__ __launch_bounds__(256) void attn_kernel(
    const unsigned short* __restrict__ qg, const unsigned short* __restrict__ kg,
    const unsigned short* __restrict__ vtg, unsigned short* __restrict__ ab) {
  __shared__ unsigned short Ksh[64 * 64];    // [s][hs], XOR-swizzled
  __shared__ unsigned short Vsh[64 * 256];   // [hs][s], XOR-swizzled
  __shared__ unsigned short Psh[4 * 16 * 256];  // per-wave [16 q][256 s], swizzled
  int bh = blockIdx.x;
  int bb = bh / H, hh = bh % H;
  int qt = blockIdx.y, q0 = qt * 64;
  int tid = threadIdx.x, lane = tid & 63, w = tid >> 6;
  int cl = lane & 15, cg = lane >> 4;
  const float scale_log2e = 0.125f * 1.44269504f;
  const unsigned short* qp = qg + ((size_t)bh * T) * HS;
  const unsigned short* kp = kg + ((size_t)bh * T) * HS;
  const unsigned short* vp = vtg + ((size_t)bh * HS) * T;

  short8 aq[2];
  #pragma unroll
  for (int k0 = 0; k0 < 2; ++k0)
    aq[k0] = *(const short8*)&qp[(size_t)(q0 + w * 16 + cl) * HS + cg * 8 + k0 * 32];

  #pragma unroll
  for (int i = 0; i < 8; ++i) {
    int idx = tid + i * 256;
    int r = idx >> 5, c16 = idx & 31;
    uint4 val = *(const uint4*)&vp[(size_t)r * T + c16 * 8];
    int byte = (r * 512 + c16 * 16) ^ ((r & 7) << 4);
    *(uint4*)((char*)Vsh + byte) = val;
  }

  float4v sacc[4][4] = {};
  for (int si = 0; si <= qt; ++si) {
    __syncthreads();
    #pragma unroll
    for (int i = 0; i < 2; ++i) {
      int idx = tid + i * 256;
      int r = idx >> 3, c16 = idx & 7;
      uint4 val = *(const uint4*)&kp[(size_t)(si * 64 + r) * HS + c16 * 8];
      int byte = (r * 128 + c16 * 16) ^ ((r & 7) << 4);
      *(uint4*)((char*)Ksh + byte) = val;
    }
    __syncthreads();
    #pragma unroll
    for (int ss = 0; ss < 4; ++ss) {
      if (ss == si) {
        #pragma unroll
        for (int nt = 0; nt < 4; ++nt) {
          int srow = nt * 16 + cl;
          #pragma unroll
          for (int k0 = 0; k0 < 2; ++k0) {
            int byte = (srow * 128 + (cg * 8 + k0 * 32) * 2) ^ ((srow & 7) << 4);
            short8 bf = *(const short8*)((char*)Ksh + byte);
            sacc[ss][nt] = __builtin_amdgcn_mfma_f32_16x16x32_bf16(aq[k0], bf, sacc[ss][nt], 0, 0, 0);
          }
        }
      }
    }
  }

  #pragma unroll
  for (int si = 0; si < 4; ++si) {
    if (si == qt) {
      #pragma unroll
      for (int nt = 0; nt < 4; ++nt) {
        int s = q0 + nt * 16 + cl;
        #pragma unroll
        for (int j = 0; j < 4; ++j) {
          int q = q0 + w * 16 + cg * 4 + j;
          if (s > q) sacc[si][nt][j] = -1e30f;
        }
      }
    }
  }

  float lj[4];
  #pragma unroll
  for (int j = 0; j < 4; ++j) {
    float m = -1e30f;
    #pragma unroll
    for (int si = 0; si < 4; ++si) if (si <= qt)
      #pragma unroll
      for (int nt = 0; nt < 4; ++nt) m = fmaxf(m, sacc[si][nt][j]);
    #pragma unroll
    for (int off = 1; off < 16; off <<= 1) m = fmaxf(m, __shfl_xor(m, off));
    float l = 0.f;
    #pragma unroll
    for (int si = 0; si < 4; ++si) if (si <= qt)
      #pragma unroll
      for (int nt = 0; nt < 4; ++nt) {
        float p0 = exp2f((sacc[si][nt][j] - m) * scale_log2e);
        sacc[si][nt][j] = p0;
        l += p0;
      }
    #pragma unroll
    for (int off = 1; off < 16; off <<= 1) l += __shfl_xor(l, off);
    lj[j] = 1.f / l;
  }

  char* pbase = (char*)Psh + w * 8192;
  #pragma unroll
  for (int si = 0; si < 4; ++si) if (si <= qt)
    #pragma unroll
    for (int nt = 0; nt < 4; ++nt)
      #pragma unroll
      for (int j = 0; j < 4; ++j) {
        int prow = cg * 4 + j, col = si * 64 + nt * 16 + cl;
        int byte = (prow * 512 + col * 2) ^ ((prow & 7) << 4);
        *(unsigned short*)(pbase + byte) = f2bf(sacc[si][nt][j]);
      }

  int nks = 2 * (qt + 1);
  #pragma unroll
  for (int nt = 0; nt < 4; ++nt) {
    float4v oacc = {};
    for (int ks = 0; ks < nks; ++ks) {
      int k = ks * 32 + cg * 8;
      int pbyte = (cl * 512 + k * 2) ^ ((cl & 7) << 4);
      short8 af = *(const short8*)(pbase + pbyte);
      int vr = nt * 16 + cl;
      int vbyte = (vr * 512 + k * 2) ^ ((vr & 7) << 4);
      short8 bf = *(const short8*)((char*)Vsh + vbyte);
      oacc = __builtin_amdgcn_mfma_f32_16x16x32_bf16(af, bf, oacc, 0, 0, 0);
    }
    #pragma unroll
    for (int j = 0; j < 4; ++j) {
      int t = q0 + w * 16 + cg * 4 + j;
      ab[((size_t)(bb * T + t)) * C + hh * 64 + nt * 16 + cl] = f2bf(oacc[j] * lj[j]);
    }
  }
}

extern "C" void kernel_launch(void* const* d_in, const int* in_sizes, int n_in,
                              void* d_out, int out_size, void* d_ws, size_t ws_size,
                              hipStream_t stream) {
  const float* x   = (const float*)d_in[0];
  const float* Wq  = (const float*)d_in[1];
  const float* Wk  = (const float*)d_in[2];
  const float* Wv  = (const float*)d_in[3];
  const float* Wo  = (const float*)d_in[4];
  const float* bo  = (const float*)d_in[5];
  const float* W1  = (const float*)d_in[6];
  const float* b1  = (const float*)d_in[7];
  const float* W2  = (const float*)d_in[8];
  const float* b2  = (const float*)d_in[9];
  const float* g1  = (const float*)d_in[10];
  const float* be1 = (const float*)d_in[11];
  const float* g2  = (const float*)d_in[12];
  const float* be2 = (const float*)d_in[13];
  float* out = (float*)d_out;
  float* ws = (float*)d_ws;

  // workspace layout (float units)
  unsigned short* wqkv_t = (unsigned short*)ws;          // 442368 sh
  unsigned short* wo_t   = wqkv_t + 442368;              // 147456 sh
  unsigned short* w1t    = wo_t + 147456;                // 589824 sh
  unsigned short* w2t    = w1t + 589824;                 // 589824 sh (tot 884736 fl)
  float* base2 = ws + 884736;
  unsigned short* h  = (unsigned short*)base2;           // 3145728 fl
  float* x2 = base2 + 3145728;                           // 6291456 fl
  unsigned short* ab = (unsigned short*)(x2 + 6291456);  // 3145728 fl
  unsigned short* qb = (unsigned short*)(x2 + 6291456 + 3145728);      // 3145728 fl
  unsigned short* kb = qb + 6291456;                     // 3145728 fl
  unsigned short* vt = kb + 6291456;                     // 3145728 fl
  unsigned short* ffb = ab;                              // reuses ab.. (12.58M fl)

  prep_w<<<1728, 256, 0, stream>>>(Wq, Wk, Wv, Wo, W1, W2, wqkv_t, wo_t, w1t, w2t);
  ln_kernel<<<BT / 4, 256, 0, stream>>>(x, g1, be1, h);
  gemm_kernel<0, 256><<<dim3(64, 9), 512, 0, stream>>>(h, wqkv_t, nullptr, nullptr,
                                                       nullptr, qb, kb, vt, 384, 1152);
  attn_kernel<<<dim3(B * H, T / 64), 256, 0, stream>>>(qb, kb, vt, ab);
  proj_ln_kernel<<<512, 512, 0, stream>>>(ab, wo_t, bo, x, g2, be2, x2, h);
  gemm_kernel<2, 256><<<dim3(64, 12), 512, 0, stream>>>(h, w1t, b1, nullptr,
                                                        nullptr, ffb, nullptr, nullptr, 384, 1536);
  gemm_kernel<3, 64><<<dim3(256, 3), 256, 0, stream>>>(ffb, w2t, b2, x2,
                                                       out, nullptr, nullptr, nullptr, 1536, 384);
}